// Round 1
// baseline (1496.425 us; speedup 1.0000x reference)
//
#include <hip/hip_runtime.h>
#include <hip/hip_bf16.h>
#include <math.h>

#define NN 50000
#define DD 64
#define MM 3
#define EE 100000
#define LL 4
#define HH 8
#define FHH 128
#define HD 512
#define NROWS (NN*MM)
#define LRELU_ALPHA 0.01f

#define Z_SZ (NN*MM*HD)            /* 76,800,000 floats */
#define DEN_SZ (NN*MM*HH)          /* 1,200,000 floats */
#define WSUM_BINS 256
#define WSUM_SZ (MM*WSUM_BINS)

__device__ __forceinline__ float elu_f(float x) {
    return x > 0.f ? x : (__expf(x) - 1.f);
}

// One wave per edge. Computes me (rotated mean), attention logits a[h],
// ex = exp(leaky_relu(a)), and atomically accumulates den[n,h] and
// num[n,h,d] += ex[h]*me[d]. Softmax max-shift is dropped (cancels exactly).
__global__ __launch_bounds__(256) void edge_kernel(
    const float* __restrict__ features,
    const float* __restrict__ attn1_w,
    const float* __restrict__ attn2,
    const float* __restrict__ r_vec,
    const int*   __restrict__ inst,
    const int*   __restrict__ etypes,
    float* __restrict__ num,
    float* __restrict__ den)
{
    const int m = blockIdx.y;
    __shared__ float frs[LL][DD/2][2];
    __shared__ float w1s[HH*DD];
    __shared__ float w2s[HH*DD];
    const int t = threadIdx.x;
    for (int i = t; i < HH*DD; i += 256) {
        w1s[i] = attn1_w[m*HD + i];
        w2s[i] = attn2[m*HD + i];
    }
    if (t < DD/2) {
        float cr = 1.f, ci = 0.f;
        frs[LL-1][t][0] = 1.f; frs[LL-1][t][1] = 0.f;
        for (int i = LL-2; i >= 0; --i) {
            int et = etypes[m*(LL-1) + i];
            float rr = r_vec[((et>>1)*(DD/2) + t)*2 + 0];
            float ri = r_vec[((et>>1)*(DD/2) + t)*2 + 1];
            float inv = rsqrtf(rr*rr + ri*ri);
            rr *= inv; ri *= inv;
            if (et & 1) ri = -ri;           // conjugate for odd types
            float nr = cr*rr - ci*ri;
            float ni = cr*ri + ci*rr;
            cr = nr; ci = ni;
            frs[i][t][0] = cr; frs[i][t][1] = ci;
        }
    }
    __syncthreads();

    const int lane = t & 63;
    const int wid  = t >> 6;
    const int p = lane >> 1;
    const float sgn = (lane & 1) ? 1.0f : -1.0f;  // im lane: +, re lane: -
    const int wave_stride = gridDim.x * 4;

    for (int e = blockIdx.x*4 + wid; e < EE; e += wave_stride) {
        const int* ip = inst + ((size_t)m*EE + e)*LL;
        float me = 0.f;
        int dst = 0;
        float x0v = 0.f;
        #pragma unroll
        for (int l = 0; l < LL; ++l) {
            int idx = ip[l];
            float x = features[idx*DD + lane];
            if (l == 0) { dst = idx; x0v = x; }
            float fx = frs[l][p][0];
            float fy = frs[l][p][1];
            float pr = __shfl_xor(x, 1);
            // re lane: x*fx - pr*fy ; im lane: x*fx + pr*fy
            me += x*fx + sgn*pr*fy;
        }
        me *= (1.0f/LL);

        float aval = 0.f;
        #pragma unroll
        for (int h = 0; h < HH; ++h) {
            float s = x0v * w1s[h*DD + lane] + me * w2s[h*DD + lane];
            s += __shfl_xor(s, 32);
            s += __shfl_xor(s, 16);
            s += __shfl_xor(s, 8);
            s += __shfl_xor(s, 4);
            s += __shfl_xor(s, 2);
            s += __shfl_xor(s, 1);
            if (lane == h) aval = s;
        }
        const int base = dst*MM + m;
        float ex = 0.f;
        if (lane < HH) {
            float aa = aval > 0.f ? aval : LRELU_ALPHA*aval;
            ex = __expf(aa);
            atomicAdd(&den[base*HH + lane], ex);
        }
        float* nump = num + base*HD + lane;
        #pragma unroll
        for (int h = 0; h < HH; ++h) {
            float exh = __shfl(ex, h);
            atomicAdd(nump + h*DD, exh * me);
        }
    }
}

// z = elu(num/den), in place over [N][M][H][D] as float4.
__global__ __launch_bounds__(256) void elu_kernel(
    float* __restrict__ z, const float* __restrict__ den)
{
    int i4 = blockIdx.x*256 + threadIdx.x;
    if (i4 >= Z_SZ/4) return;
    int nm  = i4 >> 7;          // row (n*M+m); 128 float4 per row
    int rem = i4 & 127;
    int h   = rem >> 4;         // 16 float4 per head
    float dv = den[nm*HH + h];
    float4 v = ((const float4*)z)[i4];
    float4 o;
    if (dv > 0.f) {
        float inv = 1.0f / dv;
        o.x = elu_f(v.x*inv); o.y = elu_f(v.y*inv);
        o.z = elu_f(v.z*inv); o.w = elu_f(v.w*inv);
    } else {
        o.x = o.y = o.z = o.w = 0.f;
    }
    ((float4*)z)[i4] = o;
}

// w[n,m] = w2 . tanh(W1 @ z[n,m] + b1); accumulate per-m sums (binned).
// Block: 128 threads, 16 rows, 4x4 register tiles, k-tiled W1 in LDS.
__global__ __launch_bounds__(128) void wproj_kernel(
    const float* __restrict__ z,
    const float* __restrict__ w1,
    const float* __restrict__ b1,
    const float* __restrict__ w2,
    float* __restrict__ wsum)
{
    __shared__ float zs[16*516];    // +4 pad per row: breaks 512-stride conflicts
    __shared__ float w1s[32*132];   // [kk][f], pad 132
    __shared__ float wacc[MM];
    const int t = threadIdx.x;
    const int row0 = blockIdx.x * 16;   // 150000 = 16*9375, exact
    if (t < MM) wacc[t] = 0.f;
    #pragma unroll
    for (int i = 0; i < 16; ++i) {
        int idx4 = t + 128*i;
        int r  = idx4 >> 7;
        int k4 = idx4 & 127;
        float4 v = ((const float4*)z)[(row0 + r)*128 + k4];
        *((float4*)&zs[r*516 + k4*4]) = v;
    }
    const int rg = t >> 5;
    const int fg = t & 31;
    const int r0 = rg*4;
    const int f0 = fg*4;
    float acc[4][4];
    #pragma unroll
    for (int i=0;i<4;++i)
        #pragma unroll
        for (int j=0;j<4;++j) acc[i][j]=0.f;

    for (int kt = 0; kt < 16; ++kt) {
        __syncthreads();
        #pragma unroll
        for (int i = 0; i < 8; ++i) {
            int idx4 = t + 128*i;       // 1024 float4 = 128 f x 8 kk4
            int f   = idx4 >> 3;
            int kk4 = idx4 & 7;
            float4 v = ((const float4*)w1)[f*128 + kt*8 + kk4];
            w1s[(kk4*4+0)*132 + f] = v.x;
            w1s[(kk4*4+1)*132 + f] = v.y;
            w1s[(kk4*4+2)*132 + f] = v.z;
            w1s[(kk4*4+3)*132 + f] = v.w;
        }
        __syncthreads();
        const int kbase = kt*32;
        #pragma unroll
        for (int kk4 = 0; kk4 < 8; ++kk4) {
            float4 za[4];
            float4 wa[4];
            #pragma unroll
            for (int i=0;i<4;++i)
                za[i] = *((const float4*)&zs[(r0+i)*516 + kbase + kk4*4]);
            #pragma unroll
            for (int q=0;q<4;++q)
                wa[q] = *((const float4*)&w1s[(kk4*4+q)*132 + f0]);
            #pragma unroll
            for (int i=0;i<4;++i) {
                float zx=za[i].x, zy=za[i].y, zz=za[i].z, zw=za[i].w;
                acc[i][0] += zx*wa[0].x + zy*wa[1].x + zz*wa[2].x + zw*wa[3].x;
                acc[i][1] += zx*wa[0].y + zy*wa[1].y + zz*wa[2].y + zw*wa[3].y;
                acc[i][2] += zx*wa[0].z + zy*wa[1].z + zz*wa[2].z + zw*wa[3].z;
                acc[i][3] += zx*wa[0].w + zy*wa[1].w + zz*wa[2].w + zw*wa[3].w;
            }
        }
    }

    float b1v[4], w2v[4];
    #pragma unroll
    for (int j=0;j<4;++j){ b1v[j]=b1[f0+j]; w2v[j]=w2[f0+j]; }
    #pragma unroll
    for (int i=0;i<4;++i) {
        float s = 0.f;
        #pragma unroll
        for (int j=0;j<4;++j) s += tanhf(acc[i][j] + b1v[j]) * w2v[j];
        s += __shfl_xor(s,16);
        s += __shfl_xor(s,8);
        s += __shfl_xor(s,4);
        s += __shfl_xor(s,2);
        s += __shfl_xor(s,1);
        if (fg == 0) {
            int row = row0 + r0 + i;
            atomicAdd(&wacc[row % MM], s);
        }
    }
    __syncthreads();
    if (t < MM)
        atomicAdd(&wsum[t*WSUM_BINS + (blockIdx.x & (WSUM_BINS-1))], wacc[t]);
}

__global__ void beta_kernel(const float* __restrict__ wsum, float* __restrict__ beta)
{
    __shared__ float sm[MM];
    int t = threadIdx.x;
    if (t < MM) {
        float s = 0.f;
        for (int i = 0; i < WSUM_BINS; ++i) s += wsum[t*WSUM_BINS + i];
        sm[t] = s / (float)NN;
    }
    __syncthreads();
    if (t < MM) {
        float a = sm[0], b = sm[1], c = sm[2];
        float mx = fmaxf(a, fmaxf(b, c));
        float e0 = __expf(a-mx), e1 = __expf(b-mx), e2 = __expf(c-mx);
        float tot = e0+e1+e2;
        float mine = (t==0?e0:(t==1?e1:e2));
        beta[t] = mine/tot;
    }
}

__global__ __launch_bounds__(256) void out_kernel(
    const float* __restrict__ z, const float* __restrict__ beta,
    float* __restrict__ out)
{
    int i4 = blockIdx.x*256 + threadIdx.x;   // over N*512/4
    if (i4 >= NN*128) return;
    int n  = i4 >> 7;
    int jj = i4 & 127;
    float b0 = beta[0], b1v = beta[1], b2 = beta[2];
    const float4* z4 = (const float4*)z;
    float4 v0 = z4[(n*MM+0)*128 + jj];
    float4 v1 = z4[(n*MM+1)*128 + jj];
    float4 v2 = z4[(n*MM+2)*128 + jj];
    float4 o;
    o.x = b0*v0.x + b1v*v1.x + b2*v2.x;
    o.y = b0*v0.y + b1v*v1.y + b2*v2.y;
    o.z = b0*v0.z + b1v*v1.z + b2*v2.z;
    o.w = b0*v0.w + b1v*v1.w + b2*v2.w;
    ((float4*)out)[i4] = o;
}

extern "C" void kernel_launch(void* const* d_in, const int* in_sizes, int n_in,
                              void* d_out, int out_size, void* d_ws, size_t ws_size,
                              hipStream_t stream) {
    const float* features = (const float*)d_in[0];
    const float* attn1_w  = (const float*)d_in[1];
    const float* attn2    = (const float*)d_in[2];
    const float* r_vec    = (const float*)d_in[3];
    const float* proj_w1  = (const float*)d_in[4];
    const float* proj_b1  = (const float*)d_in[5];
    const float* proj_w2  = (const float*)d_in[6];
    const int*   inst     = (const int*)d_in[7];
    const int*   etypes   = (const int*)d_in[8];
    float* out = (float*)d_out;

    float* ws   = (float*)d_ws;
    float* Z    = ws;                       // num accumulator, then z in place
    float* den  = ws + Z_SZ;
    float* wsum = ws + Z_SZ + DEN_SZ;
    float* beta = ws + Z_SZ + DEN_SZ + WSUM_SZ;

    hipMemsetAsync(Z,   0, (size_t)Z_SZ*sizeof(float), stream);
    hipMemsetAsync(den, 0, (size_t)(DEN_SZ + WSUM_SZ)*sizeof(float), stream);

    edge_kernel<<<dim3(1024, MM), 256, 0, stream>>>(
        features, attn1_w, attn2, r_vec, inst, etypes, Z, den);
    elu_kernel<<<(Z_SZ/4 + 255)/256, 256, 0, stream>>>(Z, den);
    wproj_kernel<<<NROWS/16, 128, 0, stream>>>(Z, proj_w1, proj_b1, proj_w2, wsum);
    beta_kernel<<<1, 64, 0, stream>>>(wsum, beta);
    out_kernel<<<(NN*128 + 255)/256, 256, 0, stream>>>(Z, beta, out);
}

// Round 2
// 939.065 us; speedup vs baseline: 1.5935x; 1.5935x over previous
//
#include <hip/hip_runtime.h>
#include <hip/hip_bf16.h>
#include <math.h>

#define NN 50000
#define DD 64
#define MM 3
#define EE 100000
#define LL 4
#define HH 8
#define FHH 128
#define HD 512
#define NROWS (NN*MM)
#define LRELU_ALPHA 0.01f

#define Z_SZ (NN*MM*HD)            /* 76,800,000 floats */
#define DEN_SZ (NN*MM*HH)          /* 1,200,000 floats */
#define WSUM_BINS 256
#define WSUM_SZ (MM*WSUM_BINS)
/* w1bf (bf16 copy of proj_w1) lives after beta, 16B-aligned */
#define W1BF_OFF (Z_SZ + DEN_SZ + WSUM_SZ + 16)   /* in floats; 312,003,136 B, 16B-aligned */

typedef short v8s __attribute__((ext_vector_type(8)));
typedef float v4f __attribute__((ext_vector_type(4)));

__device__ __forceinline__ float elu_f(float x) {
    return x > 0.f ? x : (__expf(x) - 1.f);
}

__device__ __forceinline__ float tanh_fast(float x) {
    float e = __expf(2.f * x);
    return 1.f - 2.f / (e + 1.f);
}

__device__ __forceinline__ unsigned int pk_bf16x2(float x, float y) {
    float2 f2; f2.x = x; f2.y = y;
    __hip_bfloat162 h = __float22bfloat162_rn(f2);
    union { __hip_bfloat162 h; unsigned int u; } cv;
    cv.h = h;
    return cv.u;
}

// One wave per edge. Computes me (rotated mean), attention logits a[h],
// ex = exp(leaky_relu(a)), and atomically accumulates den[n,h] and
// num[n,h,d] += ex[h]*me[d]. Softmax max-shift is dropped (cancels exactly).
__global__ __launch_bounds__(256) void edge_kernel(
    const float* __restrict__ features,
    const float* __restrict__ attn1_w,
    const float* __restrict__ attn2,
    const float* __restrict__ r_vec,
    const int*   __restrict__ inst,
    const int*   __restrict__ etypes,
    float* __restrict__ num,
    float* __restrict__ den)
{
    const int m = blockIdx.y;
    __shared__ float frs[LL][DD/2][2];
    __shared__ float w1s[HH*DD];
    __shared__ float w2s[HH*DD];
    const int t = threadIdx.x;
    for (int i = t; i < HH*DD; i += 256) {
        w1s[i] = attn1_w[m*HD + i];
        w2s[i] = attn2[m*HD + i];
    }
    if (t < DD/2) {
        float cr = 1.f, ci = 0.f;
        frs[LL-1][t][0] = 1.f; frs[LL-1][t][1] = 0.f;
        for (int i = LL-2; i >= 0; --i) {
            int et = etypes[m*(LL-1) + i];
            float rr = r_vec[((et>>1)*(DD/2) + t)*2 + 0];
            float ri = r_vec[((et>>1)*(DD/2) + t)*2 + 1];
            float inv = rsqrtf(rr*rr + ri*ri);
            rr *= inv; ri *= inv;
            if (et & 1) ri = -ri;           // conjugate for odd types
            float nr = cr*rr - ci*ri;
            float ni = cr*ri + ci*rr;
            cr = nr; ci = ni;
            frs[i][t][0] = cr; frs[i][t][1] = ci;
        }
    }
    __syncthreads();

    const int lane = t & 63;
    const int wid  = t >> 6;
    const int p = lane >> 1;
    const float sgn = (lane & 1) ? 1.0f : -1.0f;  // im lane: +, re lane: -
    const int wave_stride = gridDim.x * 4;

    for (int e = blockIdx.x*4 + wid; e < EE; e += wave_stride) {
        const int* ip = inst + ((size_t)m*EE + e)*LL;
        float me = 0.f;
        int dst = 0;
        float x0v = 0.f;
        #pragma unroll
        for (int l = 0; l < LL; ++l) {
            int idx = ip[l];
            float x = features[idx*DD + lane];
            if (l == 0) { dst = idx; x0v = x; }
            float fx = frs[l][p][0];
            float fy = frs[l][p][1];
            float pr = __shfl_xor(x, 1);
            me += x*fx + sgn*pr*fy;
        }
        me *= (1.0f/LL);

        float aval = 0.f;
        #pragma unroll
        for (int h = 0; h < HH; ++h) {
            float s = x0v * w1s[h*DD + lane] + me * w2s[h*DD + lane];
            s += __shfl_xor(s, 32);
            s += __shfl_xor(s, 16);
            s += __shfl_xor(s, 8);
            s += __shfl_xor(s, 4);
            s += __shfl_xor(s, 2);
            s += __shfl_xor(s, 1);
            if (lane == h) aval = s;
        }
        const int base = dst*MM + m;
        float ex = 0.f;
        if (lane < HH) {
            float aa = aval > 0.f ? aval : LRELU_ALPHA*aval;
            ex = __expf(aa);
            atomicAdd(&den[base*HH + lane], ex);
        }
        float* nump = num + base*HD + lane;
        #pragma unroll
        for (int h = 0; h < HH; ++h) {
            float exh = __shfl(ex, h);
            atomicAdd(nump + h*DD, exh * me);
        }
    }
}

// z = elu(num/den), in place over [N][M][H][D] as float4.
__global__ __launch_bounds__(256) void elu_kernel(
    float* __restrict__ z, const float* __restrict__ den)
{
    int i4 = blockIdx.x*256 + threadIdx.x;
    if (i4 >= Z_SZ/4) return;
    int nm  = i4 >> 7;          // row (n*M+m); 128 float4 per row
    int rem = i4 & 127;
    int h   = rem >> 4;         // 16 float4 per head
    float dv = den[nm*HH + h];
    float4 v = ((const float4*)z)[i4];
    float4 o;
    if (dv > 0.f) {
        float inv = 1.0f / dv;
        o.x = elu_f(v.x*inv); o.y = elu_f(v.y*inv);
        o.z = elu_f(v.z*inv); o.w = elu_f(v.w*inv);
    } else {
        o.x = o.y = o.z = o.w = 0.f;
    }
    ((float4*)z)[i4] = o;
}

// One-off: proj_w1 (128x512 fp32) -> bf16, row-major unchanged.
__global__ __launch_bounds__(64) void cvt_w1_kernel(
    const float* __restrict__ w1, ushort* __restrict__ w1bf)
{
    int i = blockIdx.x*64 + threadIdx.x;      // 16384 float4
    float4 v = ((const float4*)w1)[i];
    uint2 p;
    p.x = pk_bf16x2(v.x, v.y);
    p.y = pk_bf16x2(v.z, v.w);
    ((uint2*)w1bf)[i] = p;
}

// MFMA GEMM: C[row,f] = z[row,:] . w1[f,:], then w=sum_f tanh(C+b1)*w2,
// accumulated per-m into binned wsum. Block: 256 thr = 4 waves, 128x128 tile,
// wave tile 64x64 (4x4 MFMA 16x16x32 frags), BK=64, padded LDS (+8 bf16/row).
__global__ __launch_bounds__(256,3) void wproj_kernel(
    const float* __restrict__ z,
    const ushort* __restrict__ w1bf,
    const float* __restrict__ b1,
    const float* __restrict__ w2,
    float* __restrict__ wsum)
{
    __shared__ ushort As[128*72];   // [r][k] bf16, row stride 72 (144B)
    __shared__ ushort Bs[128*72];   // [f][k] bf16
    __shared__ float wacc[MM];
    const int t = threadIdx.x;
    const int row0 = blockIdx.x * 128;
    if (t < MM) wacc[t] = 0.f;
    const int lane = t & 63;
    const int wid  = t >> 6;
    const int ln   = lane & 15;
    const int quad = lane >> 4;
    const int wr   = wid >> 1;      // wave row half (0/1)
    const int wc   = wid & 1;       // wave col half (0/1)

    v4f acc[4][4];
    #pragma unroll
    for (int i=0;i<4;++i)
        #pragma unroll
        for (int j=0;j<4;++j)
            acc[i][j] = (v4f){0.f,0.f,0.f,0.f};

    const float4* z4  = (const float4*)z;
    const uint4*  wb4 = (const uint4*)w1bf;

    for (int kt = 0; kt < 8; ++kt) {
        __syncthreads();
        // stage A: 128 rows x 64 k fp32 -> bf16 LDS
        #pragma unroll
        for (int i = 0; i < 8; ++i) {
            int idx = t + 256*i;            // 2048 float4
            int r = idx >> 4, k4 = idx & 15;
            float4 v = {0.f,0.f,0.f,0.f};
            int gr = row0 + r;
            if (gr < NROWS) v = z4[(size_t)gr*128 + kt*16 + k4];
            uint2 p;
            p.x = pk_bf16x2(v.x, v.y);
            p.y = pk_bf16x2(v.z, v.w);
            *(uint2*)&As[r*72 + k4*4] = p;
        }
        // stage B: 128 f x 64 k bf16 (pre-converted)
        #pragma unroll
        for (int i = 0; i < 4; ++i) {
            int idx = t + 256*i;            // 1024 uint4
            int f = idx >> 3, k8 = idx & 7;
            uint4 v = wb4[f*64 + kt*8 + k8];
            *(uint4*)&Bs[f*72 + k8*8] = v;
        }
        __syncthreads();
        #pragma unroll
        for (int kk = 0; kk < 2; ++kk) {
            v8s a[4], b[4];
            #pragma unroll
            for (int i=0;i<4;++i)
                a[i] = *(const v8s*)&As[(wr*64 + i*16 + ln)*72 + kk*32 + quad*8];
            #pragma unroll
            for (int j=0;j<4;++j)
                b[j] = *(const v8s*)&Bs[(wc*64 + j*16 + ln)*72 + kk*32 + quad*8];
            #pragma unroll
            for (int i=0;i<4;++i)
                #pragma unroll
                for (int j=0;j<4;++j)
                    acc[i][j] = __builtin_amdgcn_mfma_f32_16x16x32_bf16(
                        a[i], b[j], acc[i][j], 0, 0, 0);
        }
    }

    // epilogue: per row sum_f tanh(C+b1[f])*w2[f]
    float b1v[4], w2v[4];
    #pragma unroll
    for (int j=0;j<4;++j) {
        int col = wc*64 + j*16 + ln;
        b1v[j] = b1[col];
        w2v[j] = w2[col];
    }
    #pragma unroll
    for (int i=0;i<4;++i) {
        #pragma unroll
        for (int reg=0;reg<4;++reg) {
            float s = 0.f;
            #pragma unroll
            for (int j=0;j<4;++j)
                s += tanh_fast(acc[i][j][reg] + b1v[j]) * w2v[j];
            s += __shfl_xor(s, 1);
            s += __shfl_xor(s, 2);
            s += __shfl_xor(s, 4);
            s += __shfl_xor(s, 8);
            int grow = row0 + wr*64 + i*16 + quad*4 + reg;
            if (ln == 0 && grow < NROWS)
                atomicAdd(&wacc[grow % MM], s);
        }
    }
    __syncthreads();
    if (t < MM)
        atomicAdd(&wsum[t*WSUM_BINS + (blockIdx.x & (WSUM_BINS-1))], wacc[t]);
}

__global__ void beta_kernel(const float* __restrict__ wsum, float* __restrict__ beta)
{
    __shared__ float sm[MM];
    int t = threadIdx.x;
    if (t < MM) {
        float s = 0.f;
        for (int i = 0; i < WSUM_BINS; ++i) s += wsum[t*WSUM_BINS + i];
        sm[t] = s / (float)NN;
    }
    __syncthreads();
    if (t < MM) {
        float a = sm[0], b = sm[1], c = sm[2];
        float mx = fmaxf(a, fmaxf(b, c));
        float e0 = __expf(a-mx), e1 = __expf(b-mx), e2 = __expf(c-mx);
        float tot = e0+e1+e2;
        float mine = (t==0?e0:(t==1?e1:e2));
        beta[t] = mine/tot;
    }
}

__global__ __launch_bounds__(256) void out_kernel(
    const float* __restrict__ z, const float* __restrict__ beta,
    float* __restrict__ out)
{
    int i4 = blockIdx.x*256 + threadIdx.x;   // over N*512/4
    if (i4 >= NN*128) return;
    int n  = i4 >> 7;
    int jj = i4 & 127;
    float b0 = beta[0], b1v = beta[1], b2 = beta[2];
    const float4* z4 = (const float4*)z;
    float4 v0 = z4[(n*MM+0)*128 + jj];
    float4 v1 = z4[(n*MM+1)*128 + jj];
    float4 v2 = z4[(n*MM+2)*128 + jj];
    float4 o;
    o.x = b0*v0.x + b1v*v1.x + b2*v2.x;
    o.y = b0*v0.y + b1v*v1.y + b2*v2.y;
    o.z = b0*v0.z + b1v*v1.z + b2*v2.z;
    o.w = b0*v0.w + b1v*v1.w + b2*v2.w;
    ((float4*)out)[i4] = o;
}

extern "C" void kernel_launch(void* const* d_in, const int* in_sizes, int n_in,
                              void* d_out, int out_size, void* d_ws, size_t ws_size,
                              hipStream_t stream) {
    const float* features = (const float*)d_in[0];
    const float* attn1_w  = (const float*)d_in[1];
    const float* attn2    = (const float*)d_in[2];
    const float* r_vec    = (const float*)d_in[3];
    const float* proj_w1  = (const float*)d_in[4];
    const float* proj_b1  = (const float*)d_in[5];
    const float* proj_w2  = (const float*)d_in[6];
    const int*   inst     = (const int*)d_in[7];
    const int*   etypes   = (const int*)d_in[8];
    float* out = (float*)d_out;

    float* ws    = (float*)d_ws;
    float* Z     = ws;                       // num accumulator, then z in place
    float* den   = ws + Z_SZ;
    float* wsum  = ws + Z_SZ + DEN_SZ;
    float* beta  = ws + Z_SZ + DEN_SZ + WSUM_SZ;
    ushort* w1bf = (ushort*)(ws + W1BF_OFF);

    hipMemsetAsync(Z,   0, (size_t)Z_SZ*sizeof(float), stream);
    hipMemsetAsync(den, 0, (size_t)(DEN_SZ + WSUM_SZ)*sizeof(float), stream);

    cvt_w1_kernel<<<256, 64, 0, stream>>>(proj_w1, w1bf);
    edge_kernel<<<dim3(1024, MM), 256, 0, stream>>>(
        features, attn1_w, attn2, r_vec, inst, etypes, Z, den);
    elu_kernel<<<(Z_SZ/4 + 255)/256, 256, 0, stream>>>(Z, den);
    wproj_kernel<<<(NROWS + 127)/128, 256, 0, stream>>>(Z, w1bf, proj_b1, proj_w2, wsum);
    beta_kernel<<<1, 64, 0, stream>>>(wsum, beta);
    out_kernel<<<(NN*128 + 255)/256, 256, 0, stream>>>(Z, beta, out);
}

// Round 3
// 635.561 us; speedup vs baseline: 2.3545x; 1.4775x over previous
//
#include <hip/hip_runtime.h>
#include <hip/hip_bf16.h>
#include <math.h>

#define NN 50000
#define DD 64
#define MM 3
#define EE 100000
#define LL 4
#define HH 8
#define FHH 128
#define HD 512
#define NROWS (NN*MM)
#define LRELU_ALPHA 0.01f

#define Z_SZ (NN*MM*HD)            /* 76,800,000 floats */
#define WSUM_BINS 256
#define WSUM_SZ (MM*WSUM_BINS)
#define BINS (MM*NN)               /* 150,000 */
#define NBLK ((BINS + 1023)/1024)  /* 147 */

/* workspace layout (float offsets) */
#define OFF_WSUM  Z_SZ
#define OFF_BETA  (OFF_WSUM + WSUM_SZ)
#define OFF_W1BF  (OFF_BETA + 16)            /* 32768 floats = 65536 bf16; 16B aligned */
#define OFF_INTS  (OFF_W1BF + 32768)
/* int offsets within int region */
#define IOFF_CNT    0
#define IOFF_CURSOR (IOFF_CNT + BINS)
#define IOFF_PART   (IOFF_CURSOR + BINS)
#define IOFF_BSUM   (IOFF_PART + BINS)
#define IOFF_BTOP   (IOFF_BSUM + 256)
#define IOFF_ORDER  (IOFF_BTOP + 256)

typedef short v8s __attribute__((ext_vector_type(8)));
typedef float v4f __attribute__((ext_vector_type(4)));

__device__ __forceinline__ float elu_f(float x) {
    return x > 0.f ? x : (__expf(x) - 1.f);
}

__device__ __forceinline__ float tanh_fast(float x) {
    float e = __expf(2.f * x);
    return 1.f - 2.f / (e + 1.f);
}

__device__ __forceinline__ unsigned int pk_bf16x2(float x, float y) {
    float2 f2; f2.x = x; f2.y = y;
    __hip_bfloat162 h = __float22bfloat162_rn(f2);
    union { __hip_bfloat162 h; unsigned int u; } cv;
    cv.h = h;
    return cv.u;
}

// ---------- sort-by-destination chain ----------

__global__ __launch_bounds__(256) void hist_kernel(
    const int* __restrict__ inst, int* __restrict__ cnt)
{
    int e = blockIdx.x*256 + threadIdx.x;
    int m = blockIdx.y;
    if (e >= EE) return;
    int dst = inst[((size_t)m*EE + e)*LL];
    atomicAdd(&cnt[m*NN + dst], 1);
}

// per-1024-chunk exclusive scan; block totals to bsum
__global__ __launch_bounds__(256) void scan_partial_kernel(
    const int* __restrict__ cnt, int* __restrict__ part, int* __restrict__ bsum)
{
    __shared__ int sd[256];
    const int t = threadIdx.x;
    const int base = blockIdx.x*1024 + t*4;
    int v0=0,v1=0,v2=0,v3=0;
    if (base+3 < BINS) {
        int4 v = *(const int4*)&cnt[base];
        v0=v.x; v1=v.y; v2=v.z; v3=v.w;
    } else {
        if (base+0 < BINS) v0 = cnt[base+0];
        if (base+1 < BINS) v1 = cnt[base+1];
        if (base+2 < BINS) v2 = cnt[base+2];
        if (base+3 < BINS) v3 = cnt[base+3];
    }
    int tot = v0+v1+v2+v3;
    sd[t] = tot; __syncthreads();
    #pragma unroll
    for (int off = 1; off < 256; off <<= 1) {
        int val = (t >= off) ? sd[t-off] : 0;
        __syncthreads();
        sd[t] += val;
        __syncthreads();
    }
    int excl = sd[t] - tot;
    if (base+0 < BINS) part[base+0] = excl;
    if (base+1 < BINS) part[base+1] = excl + v0;
    if (base+2 < BINS) part[base+2] = excl + v0 + v1;
    if (base+3 < BINS) part[base+3] = excl + v0 + v1 + v2;
    if (t == 255) bsum[blockIdx.x] = sd[255];
}

__global__ __launch_bounds__(256) void scan_tops_kernel(
    const int* __restrict__ bsum, int* __restrict__ btop)
{
    __shared__ int sd[256];
    const int t = threadIdx.x;
    int v = (t < NBLK) ? bsum[t] : 0;
    sd[t] = v; __syncthreads();
    #pragma unroll
    for (int off = 1; off < 256; off <<= 1) {
        int val = (t >= off) ? sd[t-off] : 0;
        __syncthreads();
        sd[t] += val;
        __syncthreads();
    }
    if (t < NBLK) btop[t] = sd[t] - v;
}

__global__ __launch_bounds__(256) void scatter_kernel(
    const int* __restrict__ inst, const int* __restrict__ part,
    const int* __restrict__ btop, int* __restrict__ cursor,
    int* __restrict__ order)
{
    int e = blockIdx.x*256 + threadIdx.x;
    int m = blockIdx.y;
    if (e >= EE) return;
    int dst = inst[((size_t)m*EE + e)*LL];
    int bin = m*NN + dst;
    int pos = part[bin] + btop[bin >> 10] + atomicAdd(&cursor[bin], 1);
    order[pos] = e;
}

// ---------- fused per-node aggregation: rotate+attention+softmax+elu ----------
// One wave per (dst node, m). No atomics, writes z row exactly once.
__global__ __launch_bounds__(256) void node_kernel(
    const float* __restrict__ features,
    const float* __restrict__ attn1_w,
    const float* __restrict__ attn2,
    const float* __restrict__ r_vec,
    const int*   __restrict__ inst,
    const int*   __restrict__ etypes,
    const int*   __restrict__ order,
    const int*   __restrict__ part,
    const int*   __restrict__ btop,
    const int*   __restrict__ cnt,
    float* __restrict__ Z)
{
    const int m = blockIdx.y;
    __shared__ float frs[LL][DD/2][2];
    __shared__ float w1s[HH*DD];
    __shared__ float w2s[HH*DD];
    const int t = threadIdx.x;
    for (int i = t; i < HH*DD; i += 256) {
        w1s[i] = attn1_w[m*HD + i];
        w2s[i] = attn2[m*HD + i];
    }
    if (t < DD/2) {
        float cr = 1.f, ci = 0.f;
        frs[LL-1][t][0] = 1.f; frs[LL-1][t][1] = 0.f;
        for (int i = LL-2; i >= 0; --i) {
            int et = etypes[m*(LL-1) + i];
            float rr = r_vec[((et>>1)*(DD/2) + t)*2 + 0];
            float ri = r_vec[((et>>1)*(DD/2) + t)*2 + 1];
            float inv = rsqrtf(rr*rr + ri*ri);
            rr *= inv; ri *= inv;
            if (et & 1) ri = -ri;
            float nr = cr*rr - ci*ri;
            float ni = cr*ri + ci*rr;
            cr = nr; ci = ni;
            frs[i][t][0] = cr; frs[i][t][1] = ci;
        }
    }
    __syncthreads();

    const int lane = t & 63;
    const int wid  = t >> 6;
    const int node = blockIdx.x*4 + wid;
    if (node >= NN) return;

    const int bin = m*NN + node;
    float* zrow = Z + ((size_t)node*MM + m)*HD;
    const int ecnt = cnt[bin];
    if (ecnt == 0) {
        #pragma unroll
        for (int h = 0; h < HH; ++h) zrow[h*DD + lane] = 0.f;
        return;
    }
    const int start = part[bin] + btop[bin >> 10];

    const int p = lane >> 1;
    const float sgn = (lane & 1) ? 1.0f : -1.0f;
    float flx[LL], fly[LL];
    #pragma unroll
    for (int l = 0; l < LL; ++l) { flx[l] = frs[l][p][0]; fly[l] = frs[l][p][1]; }

    const float x0  = features[(size_t)node*DD + lane];
    const float pr0 = __shfl_xor(x0, 1);

    // a1[h] = features[node] . attn1_w[m,h]  (held on lane h)
    float a1v = 0.f;
    #pragma unroll
    for (int h = 0; h < HH; ++h) {
        float s = x0 * w1s[h*DD + lane];
        s += __shfl_xor(s, 32);
        s += __shfl_xor(s, 16);
        s += __shfl_xor(s, 8);
        s += __shfl_xor(s, 4);
        s += __shfl_xor(s, 2);
        s += __shfl_xor(s, 1);
        if (lane == h) a1v = s;
    }

    float acc[HH];
    #pragma unroll
    for (int h = 0; h < HH; ++h) acc[h] = 0.f;
    float den = 0.f;

    for (int q = 0; q < ecnt; ++q) {
        int e = order[start + q];
        const int* ip = inst + ((size_t)m*EE + e)*LL;
        float me = x0*flx[0] + sgn*pr0*fly[0];
        #pragma unroll
        for (int l = 1; l < LL; ++l) {
            int idx = ip[l];
            float x = features[(size_t)idx*DD + lane];
            float pr = __shfl_xor(x, 1);
            me += x*flx[l] + sgn*pr*fly[l];
        }
        me *= (1.0f/LL);

        float a2v = 0.f;
        #pragma unroll
        for (int h = 0; h < HH; ++h) {
            float s = me * w2s[h*DD + lane];
            s += __shfl_xor(s, 32);
            s += __shfl_xor(s, 16);
            s += __shfl_xor(s, 8);
            s += __shfl_xor(s, 4);
            s += __shfl_xor(s, 2);
            s += __shfl_xor(s, 1);
            if (lane == h) a2v = s;
        }
        float ex = 0.f;
        if (lane < HH) {
            float a = a1v + a2v;
            a = a > 0.f ? a : LRELU_ALPHA*a;
            ex = __expf(a);
            den += ex;
        }
        #pragma unroll
        for (int h = 0; h < HH; ++h) {
            float exh = __shfl(ex, h);
            acc[h] += exh * me;
        }
    }

    #pragma unroll
    for (int h = 0; h < HH; ++h) {
        float dh = __shfl(den, h);
        zrow[h*DD + lane] = elu_f(acc[h] / dh);
    }
}

// ---------- w projection (MFMA bf16 GEMM + fused tanh/w2 epilogue) ----------

__global__ __launch_bounds__(64) void cvt_w1_kernel(
    const float* __restrict__ w1, ushort* __restrict__ w1bf)
{
    int i = blockIdx.x*64 + threadIdx.x;      // 16384 float4
    float4 v = ((const float4*)w1)[i];
    uint2 p;
    p.x = pk_bf16x2(v.x, v.y);
    p.y = pk_bf16x2(v.z, v.w);
    ((uint2*)w1bf)[i] = p;
}

__global__ __launch_bounds__(256,3) void wproj_kernel(
    const float* __restrict__ z,
    const ushort* __restrict__ w1bf,
    const float* __restrict__ b1,
    const float* __restrict__ w2,
    float* __restrict__ wsum)
{
    __shared__ ushort As[128*72];
    __shared__ ushort Bs[128*72];
    __shared__ float wacc[MM];
    const int t = threadIdx.x;
    const int row0 = blockIdx.x * 128;
    if (t < MM) wacc[t] = 0.f;
    const int lane = t & 63;
    const int wid  = t >> 6;
    const int ln   = lane & 15;
    const int quad = lane >> 4;
    const int wr   = wid >> 1;
    const int wc   = wid & 1;

    v4f acc[4][4];
    #pragma unroll
    for (int i=0;i<4;++i)
        #pragma unroll
        for (int j=0;j<4;++j)
            acc[i][j] = (v4f){0.f,0.f,0.f,0.f};

    const float4* z4  = (const float4*)z;
    const uint4*  wb4 = (const uint4*)w1bf;

    for (int kt = 0; kt < 8; ++kt) {
        __syncthreads();
        #pragma unroll
        for (int i = 0; i < 8; ++i) {
            int idx = t + 256*i;
            int r = idx >> 4, k4 = idx & 15;
            float4 v = {0.f,0.f,0.f,0.f};
            int gr = row0 + r;
            if (gr < NROWS) v = z4[(size_t)gr*128 + kt*16 + k4];
            uint2 p;
            p.x = pk_bf16x2(v.x, v.y);
            p.y = pk_bf16x2(v.z, v.w);
            *(uint2*)&As[r*72 + k4*4] = p;
        }
        #pragma unroll
        for (int i = 0; i < 4; ++i) {
            int idx = t + 256*i;
            int f = idx >> 3, k8 = idx & 7;
            uint4 v = wb4[f*64 + kt*8 + k8];
            *(uint4*)&Bs[f*72 + k8*8] = v;
        }
        __syncthreads();
        #pragma unroll
        for (int kk = 0; kk < 2; ++kk) {
            v8s a[4], b[4];
            #pragma unroll
            for (int i=0;i<4;++i)
                a[i] = *(const v8s*)&As[(wr*64 + i*16 + ln)*72 + kk*32 + quad*8];
            #pragma unroll
            for (int j=0;j<4;++j)
                b[j] = *(const v8s*)&Bs[(wc*64 + j*16 + ln)*72 + kk*32 + quad*8];
            #pragma unroll
            for (int i=0;i<4;++i)
                #pragma unroll
                for (int j=0;j<4;++j)
                    acc[i][j] = __builtin_amdgcn_mfma_f32_16x16x32_bf16(
                        a[i], b[j], acc[i][j], 0, 0, 0);
        }
    }

    float b1v[4], w2v[4];
    #pragma unroll
    for (int j=0;j<4;++j) {
        int col = wc*64 + j*16 + ln;
        b1v[j] = b1[col];
        w2v[j] = w2[col];
    }
    #pragma unroll
    for (int i=0;i<4;++i) {
        #pragma unroll
        for (int reg=0;reg<4;++reg) {
            float s = 0.f;
            #pragma unroll
            for (int j=0;j<4;++j)
                s += tanh_fast(acc[i][j][reg] + b1v[j]) * w2v[j];
            s += __shfl_xor(s, 1);
            s += __shfl_xor(s, 2);
            s += __shfl_xor(s, 4);
            s += __shfl_xor(s, 8);
            int grow = row0 + wr*64 + i*16 + quad*4 + reg;
            if (ln == 0 && grow < NROWS)
                atomicAdd(&wacc[grow % MM], s);
        }
    }
    __syncthreads();
    if (t < MM)
        atomicAdd(&wsum[t*WSUM_BINS + (blockIdx.x & (WSUM_BINS-1))], wacc[t]);
}

__global__ void beta_kernel(const float* __restrict__ wsum, float* __restrict__ beta)
{
    __shared__ float sm[MM];
    int t = threadIdx.x;
    if (t < MM) {
        float s = 0.f;
        for (int i = 0; i < WSUM_BINS; ++i) s += wsum[t*WSUM_BINS + i];
        sm[t] = s / (float)NN;
    }
    __syncthreads();
    if (t < MM) {
        float a = sm[0], b = sm[1], c = sm[2];
        float mx = fmaxf(a, fmaxf(b, c));
        float e0 = __expf(a-mx), e1 = __expf(b-mx), e2 = __expf(c-mx);
        float tot = e0+e1+e2;
        float mine = (t==0?e0:(t==1?e1:e2));
        beta[t] = mine/tot;
    }
}

__global__ __launch_bounds__(256) void out_kernel(
    const float* __restrict__ z, const float* __restrict__ beta,
    float* __restrict__ out)
{
    int i4 = blockIdx.x*256 + threadIdx.x;
    if (i4 >= NN*128) return;
    int n  = i4 >> 7;
    int jj = i4 & 127;
    float b0 = beta[0], b1v = beta[1], b2 = beta[2];
    const float4* z4 = (const float4*)z;
    float4 v0 = z4[(n*MM+0)*128 + jj];
    float4 v1 = z4[(n*MM+1)*128 + jj];
    float4 v2 = z4[(n*MM+2)*128 + jj];
    float4 o;
    o.x = b0*v0.x + b1v*v1.x + b2*v2.x;
    o.y = b0*v0.y + b1v*v1.y + b2*v2.y;
    o.z = b0*v0.z + b1v*v1.z + b2*v2.z;
    o.w = b0*v0.w + b1v*v1.w + b2*v2.w;
    ((float4*)out)[i4] = o;
}

extern "C" void kernel_launch(void* const* d_in, const int* in_sizes, int n_in,
                              void* d_out, int out_size, void* d_ws, size_t ws_size,
                              hipStream_t stream) {
    const float* features = (const float*)d_in[0];
    const float* attn1_w  = (const float*)d_in[1];
    const float* attn2    = (const float*)d_in[2];
    const float* r_vec    = (const float*)d_in[3];
    const float* proj_w1  = (const float*)d_in[4];
    const float* proj_b1  = (const float*)d_in[5];
    const float* proj_w2  = (const float*)d_in[6];
    const int*   inst     = (const int*)d_in[7];
    const int*   etypes   = (const int*)d_in[8];
    float* out = (float*)d_out;

    float* ws    = (float*)d_ws;
    float* Z     = ws;
    float* wsum  = ws + OFF_WSUM;
    float* beta  = ws + OFF_BETA;
    ushort* w1bf = (ushort*)(ws + OFF_W1BF);
    int* ints    = (int*)(ws + OFF_INTS);
    int* cnt     = ints + IOFF_CNT;
    int* cursor  = ints + IOFF_CURSOR;
    int* part    = ints + IOFF_PART;
    int* bsum    = ints + IOFF_BSUM;
    int* btop    = ints + IOFF_BTOP;
    int* order   = ints + IOFF_ORDER;

    hipMemsetAsync(cnt, 0, (size_t)2*BINS*sizeof(int), stream);     // cnt + cursor
    hipMemsetAsync(wsum, 0, (size_t)WSUM_SZ*sizeof(float), stream);

    cvt_w1_kernel<<<256, 64, 0, stream>>>(proj_w1, w1bf);
    hist_kernel<<<dim3((EE+255)/256, MM), 256, 0, stream>>>(inst, cnt);
    scan_partial_kernel<<<NBLK, 256, 0, stream>>>(cnt, part, bsum);
    scan_tops_kernel<<<1, 256, 0, stream>>>(bsum, btop);
    scatter_kernel<<<dim3((EE+255)/256, MM), 256, 0, stream>>>(inst, part, btop, cursor, order);
    node_kernel<<<dim3(NN/4, MM), 256, 0, stream>>>(
        features, attn1_w, attn2, r_vec, inst, etypes, order, part, btop, cnt, Z);
    wproj_kernel<<<(NROWS + 127)/128, 256, 0, stream>>>(Z, w1bf, proj_b1, proj_w2, wsum);
    beta_kernel<<<1, 64, 0, stream>>>(wsum, beta);
    out_kernel<<<(NN*128 + 255)/256, 256, 0, stream>>>(Z, beta, out);
}

// Round 4
// 430.428 us; speedup vs baseline: 3.4766x; 1.4766x over previous
//
#include <hip/hip_runtime.h>
#include <hip/hip_bf16.h>
#include <math.h>

#define NN 50000
#define DD 64
#define MM 3
#define EE 100000
#define LL 4
#define HH 8
#define FHH 128
#define HD 512
#define NROWS (NN*MM)
#define LRELU_ALPHA 0.01f

#define WSUM_BINS 256
#define WSUM_SZ (MM*WSUM_BINS)
#define BINS (MM*NN)               /* 150,000 */
#define NBLK ((BINS + 1023)/1024)  /* 147 */
#define GT_TILE 224

/* workspace layout (float offsets), all 16B aligned */
#define OFF_ZB    0                          /* bf16[NROWS*512] = 38.4M floats */
#define OFF_WSUM  (NROWS*HD/2)               /* 38,400,000 */
#define OFF_BETA  (OFF_WSUM + WSUM_SZ)
#define OFF_W1BF  (OFF_BETA + 16)
#define OFF_WU    (OFF_W1BF + 32768)         /* 3*32*64 = 6144 floats */
#define OFF_GT    (OFF_WU + 6144)            /* 3*50000*32 = 4.8M floats */
#define OFF_INTS  (OFF_GT + MM*NN*32)
#define IOFF_CNT    0
#define IOFF_CURSOR (IOFF_CNT + BINS)
#define IOFF_PART   (IOFF_CURSOR + BINS)
#define IOFF_BSUM   (IOFF_PART + BINS)
#define IOFF_BTOP   (IOFF_BSUM + 256)
#define IOFF_ORDER  (IOFF_BTOP + 256)

typedef short v8s __attribute__((ext_vector_type(8)));
typedef float v4f __attribute__((ext_vector_type(4)));

__device__ __forceinline__ float elu_f(float x) {
    return x > 0.f ? x : (__expf(x) - 1.f);
}

__device__ __forceinline__ float tanh_fast(float x) {
    float e = __expf(2.f * x);
    return 1.f - 2.f / (e + 1.f);
}

__device__ __forceinline__ unsigned int pk_bf16x2(float x, float y) {
    float2 f2; f2.x = x; f2.y = y;
    __hip_bfloat162 h = __float22bfloat162_rn(f2);
    union { __hip_bfloat162 h; unsigned int u; } cv;
    cv.h = h;
    return cv.u;
}

__device__ __forceinline__ float bf_lo(unsigned int u) {
    union { unsigned int x; float f; } c; c.x = u << 16; return c.f;
}
__device__ __forceinline__ float bf_hi(unsigned int u) {
    union { unsigned int x; float f; } c; c.x = u & 0xffff0000u; return c.f;
}

// compute frs chain for module m into LDS (threads 0..31)
__device__ __forceinline__ void build_frs(
    float frs[LL][DD/2][2], const float* r_vec, const int* etypes, int m, int t)
{
    if (t < DD/2) {
        float cr = 1.f, ci = 0.f;
        frs[LL-1][t][0] = 1.f; frs[LL-1][t][1] = 0.f;
        for (int i = LL-2; i >= 0; --i) {
            int et = etypes[m*(LL-1) + i];
            float rr = r_vec[((et>>1)*(DD/2) + t)*2 + 0];
            float ri = r_vec[((et>>1)*(DD/2) + t)*2 + 1];
            float inv = rsqrtf(rr*rr + ri*ri);
            rr *= inv; ri *= inv;
            if (et & 1) ri = -ri;
            float nr = cr*rr - ci*ri;
            float ni = cr*ri + ci*rr;
            cr = nr; ci = ni;
            frs[i][t][0] = cr; frs[i][t][1] = ci;
        }
    }
}

// ---------- sort-by-destination chain ----------

__global__ __launch_bounds__(256) void hist_kernel(
    const int* __restrict__ inst, int* __restrict__ cnt)
{
    int e = blockIdx.x*256 + threadIdx.x;
    int m = blockIdx.y;
    if (e >= EE) return;
    int dst = inst[((size_t)m*EE + e)*LL];
    atomicAdd(&cnt[m*NN + dst], 1);
}

__global__ __launch_bounds__(256) void scan_partial_kernel(
    const int* __restrict__ cnt, int* __restrict__ part, int* __restrict__ bsum)
{
    __shared__ int sd[256];
    const int t = threadIdx.x;
    const int base = blockIdx.x*1024 + t*4;
    int v0=0,v1=0,v2=0,v3=0;
    if (base+3 < BINS) {
        int4 v = *(const int4*)&cnt[base];
        v0=v.x; v1=v.y; v2=v.z; v3=v.w;
    } else {
        if (base+0 < BINS) v0 = cnt[base+0];
        if (base+1 < BINS) v1 = cnt[base+1];
        if (base+2 < BINS) v2 = cnt[base+2];
        if (base+3 < BINS) v3 = cnt[base+3];
    }
    int tot = v0+v1+v2+v3;
    sd[t] = tot; __syncthreads();
    #pragma unroll
    for (int off = 1; off < 256; off <<= 1) {
        int val = (t >= off) ? sd[t-off] : 0;
        __syncthreads();
        sd[t] += val;
        __syncthreads();
    }
    int excl = sd[t] - tot;
    if (base+0 < BINS) part[base+0] = excl;
    if (base+1 < BINS) part[base+1] = excl + v0;
    if (base+2 < BINS) part[base+2] = excl + v0 + v1;
    if (base+3 < BINS) part[base+3] = excl + v0 + v1 + v2;
    if (t == 255) bsum[blockIdx.x] = sd[255];
}

__global__ __launch_bounds__(256) void scan_tops_kernel(
    const int* __restrict__ bsum, int* __restrict__ btop)
{
    __shared__ int sd[256];
    const int t = threadIdx.x;
    int v = (t < NBLK) ? bsum[t] : 0;
    sd[t] = v; __syncthreads();
    #pragma unroll
    for (int off = 1; off < 256; off <<= 1) {
        int val = (t >= off) ? sd[t-off] : 0;
        __syncthreads();
        sd[t] += val;
        __syncthreads();
    }
    if (t < NBLK) btop[t] = sd[t] - v;
}

__global__ __launch_bounds__(256) void scatter_kernel(
    const int* __restrict__ inst, const int* __restrict__ part,
    const int* __restrict__ btop, int* __restrict__ cursor,
    int* __restrict__ order)
{
    int e = blockIdx.x*256 + threadIdx.x;
    int m = blockIdx.y;
    if (e >= EE) return;
    int dst = inst[((size_t)m*EE + e)*LL];
    int bin = m*NN + dst;
    int pos = part[bin] + btop[bin >> 10] + atomicAdd(&cursor[bin], 1);
    order[pos] = e;
}

// ---------- attention-weight folding ----------
// Wu[m][j][d]: j=0..7  -> attn1_w[m][j] + 0.25*u(l=0,h=j)
//             j=8..31 -> 0.25*u(l=j>>3, h=j&7)
// where u[2p]=fr*w2r+fi*w2i, u[2p+1]=fr*w2i-fi*w2r folds the rotation into attn2,
// so a[e,h] = Wu[0..7][h].x_dst + sum_{l>=1} Wu[l*8+h].x_{idx_l}
__global__ __launch_bounds__(64) void ugen_kernel(
    const float* __restrict__ r_vec,
    const int* __restrict__ etypes,
    const float* __restrict__ attn1_w,
    const float* __restrict__ attn2,
    float* __restrict__ Wu)
{
    const int m = blockIdx.x;
    __shared__ float frs[LL][DD/2][2];
    const int t = threadIdx.x;
    build_frs(frs, r_vec, etypes, m, t);
    __syncthreads();
    for (int idx = t; idx < 32*64; idx += 64) {
        int j = idx >> 6, d = idx & 63, p = d >> 1;
        int l = (j < 8) ? 0 : (j >> 3);
        int h = j & 7;
        float fr = frs[l][p][0], fi = frs[l][p][1];
        float w2r = attn2[m*HD + h*DD + 2*p];
        float w2i = attn2[m*HD + h*DD + 2*p + 1];
        float u = (d & 1) ? (fr*w2i - fi*w2r) : (fr*w2r + fi*w2i);
        float val = 0.25f * u + ((j < 8) ? attn1_w[m*HD + h*DD + d] : 0.f);
        Wu[(m*32 + j)*64 + d] = val;
    }
}

// gt[m][n][j] = features[n] . Wu[m][j]   (per-node logit table)
__global__ __launch_bounds__(256) void gt_kernel(
    const float* __restrict__ features,
    const float* __restrict__ Wu,
    float* __restrict__ gt)
{
    __shared__ float xs[GT_TILE*65];
    const int m = blockIdx.y;
    const int node0 = blockIdx.x * GT_TILE;
    const int t = threadIdx.x;
    #pragma unroll
    for (int i = 0; i < 14; ++i) {
        int idx = t + 256*i;            // 3584 float4 = 224 rows x 16
        int r = idx >> 4, c4 = idx & 15;
        int gr = node0 + r;
        float4 v = make_float4(0.f,0.f,0.f,0.f);
        if (gr < NN) v = ((const float4*)features)[gr*16 + c4];
        float* dst = &xs[r*65 + c4*4];
        dst[0]=v.x; dst[1]=v.y; dst[2]=v.z; dst[3]=v.w;
    }
    __syncthreads();
    if (t >= GT_TILE) return;
    int node = node0 + t;
    float acc[32];
    #pragma unroll
    for (int j=0;j<32;++j) acc[j]=0.f;
    const float* Wm = Wu + m*2048;
    for (int d = 0; d < 64; ++d) {
        float x = xs[t*65 + d];
        #pragma unroll
        for (int j = 0; j < 32; ++j)
            acc[j] += x * Wm[j*64 + d];
    }
    if (node < NN) {
        float* o = gt + ((size_t)m*NN + node)*32;
        #pragma unroll
        for (int j4 = 0; j4 < 8; ++j4) {
            float4 v; v.x=acc[j4*4]; v.y=acc[j4*4+1]; v.z=acc[j4*4+2]; v.w=acc[j4*4+3];
            ((float4*)o)[j4] = v;
        }
    }
}

// ---------- fused per-node aggregation ----------
// One wave per (node, m); logits from gt table (1 gather + 2 shfl per edge),
// me rotation in-register, z written once as bf16.
__global__ __launch_bounds__(256) void node_kernel(
    const float* __restrict__ features,
    const float* __restrict__ r_vec,
    const int*   __restrict__ etypes,
    const int*   __restrict__ inst,
    const int*   __restrict__ order,
    const int*   __restrict__ part,
    const int*   __restrict__ btop,
    const int*   __restrict__ cnt,
    const float* __restrict__ gt,
    ushort* __restrict__ Zb)
{
    const int m = blockIdx.y;
    __shared__ float frs[LL][DD/2][2];
    const int t = threadIdx.x;
    build_frs(frs, r_vec, etypes, m, t);
    __syncthreads();

    const int lane = t & 63;
    const int wid  = t >> 6;
    const int node = blockIdx.x*4 + wid;     // grid.x = NN/4 exact

    const int bin = m*NN + node;
    ushort* zrow = Zb + ((size_t)node*MM + m)*HD;
    const int ecnt = cnt[bin];
    if (ecnt == 0) {
        if (!(lane&1)) {
            #pragma unroll
            for (int h = 0; h < HH; ++h)
                ((unsigned int*)zrow)[h*32 + (lane>>1)] = 0u;
        }
        return;
    }
    const int start = part[bin] + btop[bin >> 10];

    const int p = lane >> 1;
    const float sgn = (lane & 1) ? 1.0f : -1.0f;
    float flx[LL], fly[LL];
    #pragma unroll
    for (int l = 0; l < LL; ++l) { flx[l] = frs[l][p][0]; fly[l] = frs[l][p][1]; }

    const float x0  = features[(size_t)node*DD + lane];
    const float pr0 = __shfl_xor(x0, 1);
    const float me0 = x0*flx[0] + sgn*pr0*fly[0];

    const float c0v = (lane < HH) ? gt[((size_t)bin)*32 + lane] : 0.f;
    const int lsel = lane >> 3;              // 1..3 valid for lanes 8..31
    const int* instm = inst + (size_t)m*EE*LL;
    const float* gtm = gt + (size_t)m*NN*32;

    float acc[HH];
    #pragma unroll
    for (int h = 0; h < HH; ++h) acc[h] = 0.f;
    float den = 0.f;

    for (int q = 0; q < ecnt; ++q) {
        int e = order[start + q];
        const int* ip = instm + e*LL;
        int i1 = ip[1], i2 = ip[2], i3 = ip[3];

        int idxg = (lsel == 1) ? i1 : ((lsel == 2) ? i2 : i3);
        float gv = 0.f;
        if (lane >= 8 && lane < 32)
            gv = gtm[(size_t)idxg*32 + lane];
        gv += __shfl_xor(gv, 16);
        gv += __shfl_xor(gv, 8);             // lanes 0..7: sum over l=1..3

        float x1 = features[(size_t)i1*DD + lane];
        float x2 = features[(size_t)i2*DD + lane];
        float x3 = features[(size_t)i3*DD + lane];
        float me = me0;
        me += x1*flx[1] + sgn*__shfl_xor(x1,1)*fly[1];
        me += x2*flx[2] + sgn*__shfl_xor(x2,1)*fly[2];
        me += x3*flx[3] + sgn*__shfl_xor(x3,1)*fly[3];
        me *= 0.25f;

        float ex = 0.f;
        if (lane < HH) {
            float a = c0v + gv;
            a = a > 0.f ? a : LRELU_ALPHA*a;
            ex = __expf(a);
            den += ex;
        }
        #pragma unroll
        for (int h = 0; h < HH; ++h)
            acc[h] += __shfl(ex, h) * me;
    }

    #pragma unroll
    for (int h = 0; h < HH; ++h) {
        float dh = __shfl(den, h);
        float v = elu_f(acc[h] / dh);
        float vn = __shfl_xor(v, 1);
        if (!(lane&1))
            ((unsigned int*)zrow)[h*32 + (lane>>1)] = pk_bf16x2(v, vn);
    }
}

// ---------- w projection (MFMA bf16 GEMM + fused tanh/w2 epilogue) ----------

__global__ __launch_bounds__(64) void cvt_w1_kernel(
    const float* __restrict__ w1, ushort* __restrict__ w1bf)
{
    int i = blockIdx.x*64 + threadIdx.x;
    float4 v = ((const float4*)w1)[i];
    uint2 p;
    p.x = pk_bf16x2(v.x, v.y);
    p.y = pk_bf16x2(v.z, v.w);
    ((uint2*)w1bf)[i] = p;
}

__global__ __launch_bounds__(256,3) void wproj_kernel(
    const ushort* __restrict__ Zb,
    const ushort* __restrict__ w1bf,
    const float* __restrict__ b1,
    const float* __restrict__ w2,
    float* __restrict__ wsum)
{
    __shared__ ushort As[128*72];
    __shared__ ushort Bs[128*72];
    __shared__ float wacc[MM];
    const int t = threadIdx.x;
    const int row0 = blockIdx.x * 128;
    if (t < MM) wacc[t] = 0.f;
    const int lane = t & 63;
    const int wid  = t >> 6;
    const int ln   = lane & 15;
    const int quad = lane >> 4;
    const int wr   = wid >> 1;
    const int wc   = wid & 1;

    v4f acc[4][4];
    #pragma unroll
    for (int i=0;i<4;++i)
        #pragma unroll
        for (int j=0;j<4;++j)
            acc[i][j] = (v4f){0.f,0.f,0.f,0.f};

    const uint4* zb4 = (const uint4*)Zb;     // 8 bf16 per uint4; row = 64 uint4
    const uint4* wb4 = (const uint4*)w1bf;

    for (int kt = 0; kt < 8; ++kt) {
        __syncthreads();
        #pragma unroll
        for (int i = 0; i < 4; ++i) {
            int idx = t + 256*i;            // 1024 uint4 = 128 rows x 8
            int r = idx >> 3, k8 = idx & 7;
            int gr = row0 + r;
            uint4 v = make_uint4(0u,0u,0u,0u);
            if (gr < NROWS) v = zb4[(size_t)gr*64 + kt*8 + k8];
            *(uint4*)&As[r*72 + k8*8] = v;
        }
        #pragma unroll
        for (int i = 0; i < 4; ++i) {
            int idx = t + 256*i;
            int f = idx >> 3, k8 = idx & 7;
            uint4 v = wb4[f*64 + kt*8 + k8];
            *(uint4*)&Bs[f*72 + k8*8] = v;
        }
        __syncthreads();
        #pragma unroll
        for (int kk = 0; kk < 2; ++kk) {
            v8s a[4], b[4];
            #pragma unroll
            for (int i=0;i<4;++i)
                a[i] = *(const v8s*)&As[(wr*64 + i*16 + ln)*72 + kk*32 + quad*8];
            #pragma unroll
            for (int j=0;j<4;++j)
                b[j] = *(const v8s*)&Bs[(wc*64 + j*16 + ln)*72 + kk*32 + quad*8];
            #pragma unroll
            for (int i=0;i<4;++i)
                #pragma unroll
                for (int j=0;j<4;++j)
                    acc[i][j] = __builtin_amdgcn_mfma_f32_16x16x32_bf16(
                        a[i], b[j], acc[i][j], 0, 0, 0);
        }
    }

    float b1v[4], w2v[4];
    #pragma unroll
    for (int j=0;j<4;++j) {
        int col = wc*64 + j*16 + ln;
        b1v[j] = b1[col];
        w2v[j] = w2[col];
    }
    #pragma unroll
    for (int i=0;i<4;++i) {
        #pragma unroll
        for (int reg=0;reg<4;++reg) {
            float s = 0.f;
            #pragma unroll
            for (int j=0;j<4;++j)
                s += tanh_fast(acc[i][j][reg] + b1v[j]) * w2v[j];
            s += __shfl_xor(s, 1);
            s += __shfl_xor(s, 2);
            s += __shfl_xor(s, 4);
            s += __shfl_xor(s, 8);
            int grow = row0 + wr*64 + i*16 + quad*4 + reg;
            if (ln == 0 && grow < NROWS)
                atomicAdd(&wacc[grow % MM], s);
        }
    }
    __syncthreads();
    if (t < MM)
        atomicAdd(&wsum[t*WSUM_BINS + (blockIdx.x & (WSUM_BINS-1))], wacc[t]);
}

__global__ void beta_kernel(const float* __restrict__ wsum, float* __restrict__ beta)
{
    __shared__ float sm[MM];
    int t = threadIdx.x;
    if (t < MM) {
        float s = 0.f;
        for (int i = 0; i < WSUM_BINS; ++i) s += wsum[t*WSUM_BINS + i];
        sm[t] = s / (float)NN;
    }
    __syncthreads();
    if (t < MM) {
        float a = sm[0], b = sm[1], c = sm[2];
        float mx = fmaxf(a, fmaxf(b, c));
        float e0 = __expf(a-mx), e1 = __expf(b-mx), e2 = __expf(c-mx);
        float tot = e0+e1+e2;
        float mine = (t==0?e0:(t==1?e1:e2));
        beta[t] = mine/tot;
    }
}

__global__ __launch_bounds__(256) void out_kernel(
    const ushort* __restrict__ Zb, const float* __restrict__ beta,
    float* __restrict__ out)
{
    int i = blockIdx.x*256 + threadIdx.x;    // NN*64 threads, 8 outputs each
    int n  = i >> 6;
    int jj = i & 63;
    float b0 = beta[0], b1v = beta[1], b2 = beta[2];
    const uint4* zb4 = (const uint4*)Zb;
    uint4 v0 = zb4[((size_t)n*MM + 0)*64 + jj];
    uint4 v1 = zb4[((size_t)n*MM + 1)*64 + jj];
    uint4 v2 = zb4[((size_t)n*MM + 2)*64 + jj];
    float o[8];
    o[0] = b0*bf_lo(v0.x) + b1v*bf_lo(v1.x) + b2*bf_lo(v2.x);
    o[1] = b0*bf_hi(v0.x) + b1v*bf_hi(v1.x) + b2*bf_hi(v2.x);
    o[2] = b0*bf_lo(v0.y) + b1v*bf_lo(v1.y) + b2*bf_lo(v2.y);
    o[3] = b0*bf_hi(v0.y) + b1v*bf_hi(v1.y) + b2*bf_hi(v2.y);
    o[4] = b0*bf_lo(v0.z) + b1v*bf_lo(v1.z) + b2*bf_lo(v2.z);
    o[5] = b0*bf_hi(v0.z) + b1v*bf_hi(v1.z) + b2*bf_hi(v2.z);
    o[6] = b0*bf_lo(v0.w) + b1v*bf_lo(v1.w) + b2*bf_lo(v2.w);
    o[7] = b0*bf_hi(v0.w) + b1v*bf_hi(v1.w) + b2*bf_hi(v2.w);
    float4* op = (float4*)(out + (size_t)n*HD + jj*8);
    op[0] = make_float4(o[0],o[1],o[2],o[3]);
    op[1] = make_float4(o[4],o[5],o[6],o[7]);
}

extern "C" void kernel_launch(void* const* d_in, const int* in_sizes, int n_in,
                              void* d_out, int out_size, void* d_ws, size_t ws_size,
                              hipStream_t stream) {
    const float* features = (const float*)d_in[0];
    const float* attn1_w  = (const float*)d_in[1];
    const float* attn2    = (const float*)d_in[2];
    const float* r_vec    = (const float*)d_in[3];
    const float* proj_w1  = (const float*)d_in[4];
    const float* proj_b1  = (const float*)d_in[5];
    const float* proj_w2  = (const float*)d_in[6];
    const int*   inst     = (const int*)d_in[7];
    const int*   etypes   = (const int*)d_in[8];
    float* out = (float*)d_out;

    float* ws    = (float*)d_ws;
    ushort* Zb   = (ushort*)(ws + OFF_ZB);
    float* wsum  = ws + OFF_WSUM;
    float* beta  = ws + OFF_BETA;
    ushort* w1bf = (ushort*)(ws + OFF_W1BF);
    float* Wu    = ws + OFF_WU;
    float* gt    = ws + OFF_GT;
    int* ints    = (int*)(ws + OFF_INTS);
    int* cnt     = ints + IOFF_CNT;
    int* cursor  = ints + IOFF_CURSOR;
    int* part    = ints + IOFF_PART;
    int* bsum    = ints + IOFF_BSUM;
    int* btop    = ints + IOFF_BTOP;
    int* order   = ints + IOFF_ORDER;

    hipMemsetAsync(cnt, 0, (size_t)2*BINS*sizeof(int), stream);
    hipMemsetAsync(wsum, 0, (size_t)WSUM_SZ*sizeof(float), stream);

    cvt_w1_kernel<<<256, 64, 0, stream>>>(proj_w1, w1bf);
    ugen_kernel<<<MM, 64, 0, stream>>>(r_vec, etypes, attn1_w, attn2, Wu);
    gt_kernel<<<dim3((NN + GT_TILE-1)/GT_TILE, MM), 256, 0, stream>>>(features, Wu, gt);
    hist_kernel<<<dim3((EE+255)/256, MM), 256, 0, stream>>>(inst, cnt);
    scan_partial_kernel<<<NBLK, 256, 0, stream>>>(cnt, part, bsum);
    scan_tops_kernel<<<1, 256, 0, stream>>>(bsum, btop);
    scatter_kernel<<<dim3((EE+255)/256, MM), 256, 0, stream>>>(inst, part, btop, cursor, order);
    node_kernel<<<dim3(NN/4, MM), 256, 0, stream>>>(
        features, r_vec, etypes, inst, order, part, btop, cnt, gt, Zb);
    wproj_kernel<<<(NROWS + 127)/128, 256, 0, stream>>>(Zb, w1bf, proj_b1, proj_w2, wsum);
    beta_kernel<<<1, 64, 0, stream>>>(wsum, beta);
    out_kernel<<<NN*64/256, 256, 0, stream>>>(Zb, beta, out);
}